// Round 15
// baseline (77.966 us; speedup 1.0000x reference)
//
#include <hip/hip_runtime.h>
#include <math.h>

#define BB 256
#define NF 512
#define IND 64
#define HD 128
#define SS 51
#define NHM1 63

// ws float offsets
#define WS_LAM  0
#define WS_CCW  16
#define WS_U    80
#define WS_XM   144
#define WS_OUT1 656
// ws half (short) offsets
#define WSH_C1  2048        // c1 f16 [256][128]
#define WSH_W1  34816       // w1t f16 [128]
#define WSH_W2F 40960       // W2 f16 fragment table [16384]

typedef _Float16 f16x2 __attribute__((ext_vector_type(2)));
typedef __fp16   fp16x2 __attribute__((ext_vector_type(2)));
typedef _Float16 f16x8 __attribute__((ext_vector_type(8)));
typedef float    f32x16 __attribute__((ext_vector_type(16)));

union f16x8_split { f16x8 v8; f16x2 v2[4]; };
union pk_cast { fp16x2 p; f16x2 f; };

static __device__ inline f16x2 cvt_pk(float a, float b) {
    pk_cast u; u.p = __builtin_amdgcn_cvt_pkrtz(a, b);
    return u.f;
}

static __device__ inline float dot2f(f16x2 a, f16x2 b, float c) {
#if __has_builtin(__builtin_amdgcn_fdot2)
    return __builtin_amdgcn_fdot2(a, b, c, false);
#else
    return c + (float)a[0] * (float)b[0] + (float)a[1] * (float)b[1];
#endif
}

__global__ void k_setup(const float* __restrict__ x_, const float* __restrict__ h_,
                        const float* __restrict__ W1, const float* __restrict__ b1,
                        const float* __restrict__ W2, const float* __restrict__ lw,
                        const float* __restrict__ sp, float* __restrict__ ws) {
    int b = blockIdx.x;
    int j = threadIdx.x;  // 128 threads
    short* wsh = (short*)ws;

    // c1[b][j] = b1[j] + sum_k W1[j][1+k] * h_[b][k]   (stored f16)
    float acc = b1[j];
    const float* w1row = W1 + j * IND;
    const float* hrow  = h_ + b * NHM1;
    #pragma unroll 7
    for (int k = 0; k < NHM1; ++k) acc = fmaf(w1row[1 + k], hrow[k], acc);
    {
        _Float16 hv = (_Float16)acc;
        short sv; __builtin_memcpy(&sv, &hv, 2);
        wsh[WSH_C1 + b * HD + j] = sv;
    }

    // xm[b] = sum_f x_[b][f] * lw[f]
    float s = 0.f;
    for (int k = j; k < NF; k += HD) s = fmaf(x_[b * NF + k], lw[k], s);
    __shared__ float red[HD];
    red[j] = s;
    __syncthreads();
    for (int off = 64; off > 0; off >>= 1) {
        if (j < off) red[j] += red[j + off];
        __syncthreads();
    }
    if (j == 0) ws[WS_XM + b] = red[0];

    // W2 fragment pack (A layout, 32x32x16):
    // table[((kk*4+nt)*64 + lane)*8 + i] = f16(W2[nt*32+(lane&31)][kk*16+(lane>>5)*8+i])
    if (b < 128) {
        int d = b * 128 + j;   // 0..16383
        int i = d & 7, lane = (d >> 3) & 63, kn = d >> 9;
        int kk = kn >> 2, nt = kn & 3;
        int row = nt * 32 + (lane & 31);
        int k = kk * 16 + (lane >> 5) * 8 + i;
        _Float16 hv = (_Float16)W2[row * HD + k];
        short sv; __builtin_memcpy(&sv, &hv, 2);
        wsh[WSH_W2F + d] = sv;
    }

    if (b == 0) {
        if (j < SS) {
            float acc2 = 0.f;
            for (int jj = 0; jj <= 50; jj += 2) {
                float wj = (jj == 0) ? 1.f : 2.f / (1.f - (float)(jj * jj));
                float lamv;
                if (j == 0 || j == 50) {
                    lamv = 0.02f;
                } else {
                    int m = (jj * j) % 100;
                    lamv = cosf((float)m * (float)M_PI / 50.f) * 0.04f;
                }
                acc2 = fmaf(lamv, wj, acc2);
            }
            ws[WS_CCW + j] = acc2;
            float st = cosf((float)j * (float)M_PI / 50.f);
            ws[WS_U + j] = (st + 1.f) * 0.5f;
        }
        if (j == 127) ws[WS_LAM] = 1.f / (1.f + expf(-sp[0]));
    }
    if (b == 2) {
        _Float16 hv = (_Float16)W1[j * IND];   // w1t column as f16
        short sv; __builtin_memcpy(&sv, &hv, 2);
        wsh[WSH_W1 + j] = sv;
    }
    if (b == 4) ws[WS_OUT1 + j] = 0.f;
    if (b == 5) ws[WS_OUT1 + 128 + j] = 0.f;
}

// r9 structure + 2x ILP: one block = one batch row; 4 INDEPENDENT waves.
// Wave owns 21 tiles of 32 evals, processed TWO per iteration (11 dbl-iters,
// last half-tile weight-masked). All state in registers: Af 128 + c1/w1 64 +
// b2/w3 packed 64 + C 2x64. 64 MFMAs / 8 interleaved chains per dbl-iter;
// two overlapped epilogues + two deferred tails. No LDS / barriers in loop.
__launch_bounds__(256, 1)
__global__ void k_int(const float* __restrict__ b2, const float* __restrict__ W3,
                      const float* __restrict__ b3, const float* __restrict__ fw,
                      const float* __restrict__ ws, const float* __restrict__ outprev,
                      float* __restrict__ tgt, float* __restrict__ ztgt) {
    int b = blockIdx.x;
    int tid = threadIdx.x;
    int wv = tid >> 6, l = tid & 63;
    int e32 = l & 31, h2 = l >> 5;

    __shared__ float us[SS], ccs[SS], xw[4];

    if (ztgt && tid == 0) ztgt[b] = 0.f;   // zero next-step accumulator
    if (tid < SS) { us[tid] = ws[WS_U + tid]; ccs[tid] = ws[WS_CCW + tid]; }

    // xT / xmax prologue: xmax = max(0, max_b xT[b]) + 10
    float lam = ws[WS_LAM];
    float xmv = ws[WS_XM + tid];
    float opv = outprev ? outprev[tid] : 0.f;
    float xtv = (1.f - lam) * xmv + lam * opv;
    float mx = fmaxf(xtv, 0.f);
    #pragma unroll
    for (int off = 32; off >= 1; off >>= 1) mx = fmaxf(mx, __shfl_xor(mx, off, 64));
    if (l == 0) xw[wv] = mx;
    __syncthreads();
    float xmax = fmaxf(fmaxf(xw[0], xw[1]), fmaxf(xw[2], xw[3])) + 10.f;
    float xT = (1.f - lam) * ws[WS_XM + b] + lam * (outprev ? outprev[b] : 0.f);

    const short* wsh = (const short*)ws;

    // stationary: full W2 fragment set (128 regs)
    f16x8 Af[8][4];
    #pragma unroll
    for (int kk = 0; kk < 8; ++kk)
        #pragma unroll
        for (int nt = 0; nt < 4; ++nt)
            Af[kk][nt] = *reinterpret_cast<const f16x8*>(
                wsh + WSH_W2F + ((kk * 4 + nt) * 64 + l) * 8);

    f16x2 c1p[8][4], w1p[8][4];
    #pragma unroll
    for (int kk = 0; kk < 8; ++kk) {
        f16x8_split c8, w8;
        c8.v8 = *reinterpret_cast<const f16x8*>(wsh + WSH_C1 + b * HD + kk * 16 + h2 * 8);
        w8.v8 = *reinterpret_cast<const f16x8*>(wsh + WSH_W1 + kk * 16 + h2 * 8);
        #pragma unroll
        for (int p = 0; p < 4; ++p) { c1p[kk][p] = c8.v2[p]; w1p[kk][p] = w8.v2[p]; }
    }

    // b2 / w3 packed f16x2 in fragment order (reg pair q covers rows 2q, 2q+1)
    f16x2 b2pk[4][8], w3pk[4][8];
    #pragma unroll
    for (int nt = 0; nt < 4; ++nt) {
        int jb = nt * 32;
        #pragma unroll
        for (int q = 0; q < 8; ++q) {
            int r0 = ((2 * q) & 3) + 8 * ((2 * q) >> 2) + 4 * h2;
            b2pk[nt][q] = cvt_pk(b2[jb + r0], b2[jb + r0 + 1]);
            w3pk[nt][q] = cvt_pk(W3[jb + r0], W3[jb + r0 + 1]);
        }
    }
    float b3v = b3[0];
    float fw0 = fw[0], fw1 = fw[1], fw2 = fw[2], fw3 = fw[3], fw4 = fw[4];

    float accO = 0.f;
    float zsA = 0.f, wA = 0.f, zsB = 0.f, wB = 0.f;   // deferred-tail carries
    const f16x2 z2 = {(_Float16)0.f, (_Float16)0.f};

    #pragma unroll 1
    for (int d = 0; d < 11; ++d) {
        // two tiles: it0 = 2d, it1 = 2d+1 (it1 = 21 at d = 10: weight-masked pad)
        float t0, t1, ws0, ws1;
        #pragma unroll
        for (int p = 0; p < 2; ++p) {
            int itp = 2 * d + p;
            int m = (wv * 21 + itp) * 32 + e32;
            int valid = (itp < 21) && (m <= 2600);
            int mm = (m <= 2600) ? m : 2600;
            int s  = (mm * 41121) >> 21;        // mm / 51 (exact for mm < 110376)
            int si = mm - s * 51;
            float x = xT * us[s];
            float range = xmax - x;
            float t = fmaf(range, us[si], x);
            float wgt = valid ? (ccs[si] * ccs[s] * range * xT * 0.25f) : 0.f;
            float wsel = h2 ? 0.f : wgt;        // h2=1 lanes duplicate -> contribute 0
            if (p == 0) { t0 = t; ws0 = wsel; } else { t1 = t; ws1 = wsel; }
        }
        _Float16 th0 = (_Float16)t0, th1 = (_Float16)t1;
        f16x2 tv0 = {th0, th0}, tv1 = {th1, th1};

        f32x16 C0, C1, C2, C3, C4, C5, C6, C7;
        #pragma unroll
        for (int e = 0; e < 16; ++e) {
            C0[e] = 0.f; C1[e] = 0.f; C2[e] = 0.f; C3[e] = 0.f;
            C4[e] = 0.f; C5[e] = 0.f; C6[e] = 0.f; C7[e] = 0.f;
        }

        // deferred tails for previous dbl-iter (overlap this iter's MFMAs)
        {
            float z = zsA > 0.f ? zsA + 1.f : __expf(zsA);
            float sq = sqrtf(z);
            float p15 = z * sq, p2 = z * z, p25 = p2 * sq, p3 = p2 * z, p35 = p3 * sq;
            float g = fw0 * __builtin_amdgcn_rcpf(p15 + 1.f)
                    + fw1 * __builtin_amdgcn_rcpf(p2  + 1.f)
                    + fw2 * __builtin_amdgcn_rcpf(p25 + 1.f)
                    + fw3 * __builtin_amdgcn_rcpf(p3  + 1.f)
                    + fw4 * __builtin_amdgcn_rcpf(p35 + 1.f);
            accO = fmaf(fmaxf(g, 0.f), wA, accO);
            z = zsB > 0.f ? zsB + 1.f : __expf(zsB);
            sq = sqrtf(z);
            p15 = z * sq; p2 = z * z; p25 = p2 * sq; p3 = p2 * z; p35 = p3 * sq;
            g = fw0 * __builtin_amdgcn_rcpf(p15 + 1.f)
              + fw1 * __builtin_amdgcn_rcpf(p2  + 1.f)
              + fw2 * __builtin_amdgcn_rcpf(p25 + 1.f)
              + fw3 * __builtin_amdgcn_rcpf(p3  + 1.f)
              + fw4 * __builtin_amdgcn_rcpf(p35 + 1.f);
            accO = fmaf(fmaxf(g, 0.f), wB, accO);
        }

        #pragma unroll
        for (int kk = 0; kk < 8; ++kk) {
            f16x8_split Bu0, Bu1;
            #pragma unroll
            for (int p = 0; p < 4; ++p) {
                Bu0.v2[p] = __builtin_elementwise_max(
                    __builtin_elementwise_fma(w1p[kk][p], tv0, c1p[kk][p]), z2);
                Bu1.v2[p] = __builtin_elementwise_max(
                    __builtin_elementwise_fma(w1p[kk][p], tv1, c1p[kk][p]), z2);
            }
            C0 = __builtin_amdgcn_mfma_f32_32x32x16_f16(Af[kk][0], Bu0.v8, C0, 0, 0, 0);
            C4 = __builtin_amdgcn_mfma_f32_32x32x16_f16(Af[kk][0], Bu1.v8, C4, 0, 0, 0);
            C1 = __builtin_amdgcn_mfma_f32_32x32x16_f16(Af[kk][1], Bu0.v8, C1, 0, 0, 0);
            C5 = __builtin_amdgcn_mfma_f32_32x32x16_f16(Af[kk][1], Bu1.v8, C5, 0, 0, 0);
            C2 = __builtin_amdgcn_mfma_f32_32x32x16_f16(Af[kk][2], Bu0.v8, C2, 0, 0, 0);
            C6 = __builtin_amdgcn_mfma_f32_32x32x16_f16(Af[kk][2], Bu1.v8, C6, 0, 0, 0);
            C3 = __builtin_amdgcn_mfma_f32_32x32x16_f16(Af[kk][3], Bu0.v8, C3, 0, 0, 0);
            C7 = __builtin_amdgcn_mfma_f32_32x32x16_f16(Af[kk][3], Bu1.v8, C7, 0, 0, 0);
        }

        // epilogue tile0
        {
            float za = 0.f, zb = 0.f, zc = 0.f, zd = 0.f;
            #pragma unroll
            for (int q = 0; q < 8; ++q) {
                f16x2 a0 = cvt_pk(C0[2 * q], C0[2 * q + 1]);
                a0 = __builtin_elementwise_max(a0 + b2pk[0][q], z2);
                za = dot2f(a0, w3pk[0][q], za);
                f16x2 a1 = cvt_pk(C1[2 * q], C1[2 * q + 1]);
                a1 = __builtin_elementwise_max(a1 + b2pk[1][q], z2);
                zb = dot2f(a1, w3pk[1][q], zb);
                f16x2 a2 = cvt_pk(C2[2 * q], C2[2 * q + 1]);
                a2 = __builtin_elementwise_max(a2 + b2pk[2][q], z2);
                zc = dot2f(a2, w3pk[2][q], zc);
                f16x2 a3 = cvt_pk(C3[2 * q], C3[2 * q + 1]);
                a3 = __builtin_elementwise_max(a3 + b2pk[3][q], z2);
                zd = dot2f(a3, w3pk[3][q], zd);
            }
            float z1 = (za + zb) + (zc + zd);
            z1 += __shfl_xor(z1, 32, 64);       // fold h-halves
            zsA = z1 + b3v;
            wA = ws0;
        }
        // epilogue tile1
        {
            float za = 0.f, zb = 0.f, zc = 0.f, zd = 0.f;
            #pragma unroll
            for (int q = 0; q < 8; ++q) {
                f16x2 a0 = cvt_pk(C4[2 * q], C4[2 * q + 1]);
                a0 = __builtin_elementwise_max(a0 + b2pk[0][q], z2);
                za = dot2f(a0, w3pk[0][q], za);
                f16x2 a1 = cvt_pk(C5[2 * q], C5[2 * q + 1]);
                a1 = __builtin_elementwise_max(a1 + b2pk[1][q], z2);
                zb = dot2f(a1, w3pk[1][q], zb);
                f16x2 a2 = cvt_pk(C6[2 * q], C6[2 * q + 1]);
                a2 = __builtin_elementwise_max(a2 + b2pk[2][q], z2);
                zc = dot2f(a2, w3pk[2][q], zc);
                f16x2 a3 = cvt_pk(C7[2 * q], C7[2 * q + 1]);
                a3 = __builtin_elementwise_max(a3 + b2pk[3][q], z2);
                zd = dot2f(a3, w3pk[3][q], zd);
            }
            float z1 = (za + zb) + (zc + zd);
            z1 += __shfl_xor(z1, 32, 64);
            zsB = z1 + b3v;
            wB = ws1;
        }
    }

    // final tails (dbl-iter 10)
    {
        float z = zsA > 0.f ? zsA + 1.f : __expf(zsA);
        float sq = sqrtf(z);
        float p15 = z * sq, p2 = z * z, p25 = p2 * sq, p3 = p2 * z, p35 = p3 * sq;
        float g = fw0 * __builtin_amdgcn_rcpf(p15 + 1.f)
                + fw1 * __builtin_amdgcn_rcpf(p2  + 1.f)
                + fw2 * __builtin_amdgcn_rcpf(p25 + 1.f)
                + fw3 * __builtin_amdgcn_rcpf(p3  + 1.f)
                + fw4 * __builtin_amdgcn_rcpf(p35 + 1.f);
        accO = fmaf(fmaxf(g, 0.f), wA, accO);
        z = zsB > 0.f ? zsB + 1.f : __expf(zsB);
        sq = sqrtf(z);
        p15 = z * sq; p2 = z * z; p25 = p2 * sq; p3 = p2 * z; p35 = p3 * sq;
        g = fw0 * __builtin_amdgcn_rcpf(p15 + 1.f)
          + fw1 * __builtin_amdgcn_rcpf(p2  + 1.f)
          + fw2 * __builtin_amdgcn_rcpf(p25 + 1.f)
          + fw3 * __builtin_amdgcn_rcpf(p3  + 1.f)
          + fw4 * __builtin_amdgcn_rcpf(p35 + 1.f);
        accO = fmaf(fmaxf(g, 0.f), wB, accO);
    }

    // wave-level reduce (h2=1 lanes hold 0), one atomic per wave
    #pragma unroll
    for (int off = 32; off >= 1; off >>= 1) accO += __shfl_xor(accO, off, 64);
    if (l == 0) atomicAdd(&tgt[b], accO);
}

extern "C" void kernel_launch(void* const* d_in, const int* in_sizes, int n_in,
                              void* d_out, int out_size, void* d_ws, size_t ws_size,
                              hipStream_t stream) {
    (void)in_sizes; (void)n_in; (void)out_size; (void)ws_size;
    const float* x_ = (const float*)d_in[0];
    const float* h_ = (const float*)d_in[1];
    const float* W1 = (const float*)d_in[2];
    const float* b1 = (const float*)d_in[3];
    const float* W2 = (const float*)d_in[4];
    const float* b2 = (const float*)d_in[5];
    const float* W3 = (const float*)d_in[6];
    const float* b3 = (const float*)d_in[7];
    const float* fw = (const float*)d_in[8];
    const float* lw = (const float*)d_in[9];
    const float* sp = (const float*)d_in[10];
    float* wsf  = (float*)d_ws;
    float* out1 = wsf + WS_OUT1;
    float* out  = (float*)d_out;

    // setup: c1, xm, CC tables, lam, W2 fragment pack, zero out1
    k_setup<<<BB, HD, 0, stream>>>(x_, h_, W1, b1, W2, lw, sp, wsf);
    // RNN step 0: xT=(1-lam)*xm (outprev=null); accumulate into out1; zero d_out
    k_int<<<BB, 256, 0, stream>>>(b2, W3, b3, fw, wsf, nullptr, out1, out);
    // RNN step 1: xT=(1-lam)*xm+lam*out1; accumulate into d_out
    k_int<<<BB, 256, 0, stream>>>(b2, W3, b3, fw, wsf, out1, out, nullptr);
}

// Round 16
// 73.130 us; speedup vs baseline: 1.0661x; 1.0661x over previous
//
#include <hip/hip_runtime.h>
#include <math.h>

#define BB 256
#define NF 512
#define IND 64
#define HD 128
#define SS 51
#define NHM1 63

// ws float offsets
#define WS_LAM  0
#define WS_CCW  16
#define WS_U    80
#define WS_XM   144
#define WS_OUT1 656
// ws half (short) offsets
#define WSH_C1  2048        // c1 f16 [256][128]
#define WSH_W1  34816       // w1t f16 [128]
#define WSH_W2F 40960       // W2 f16 fragment table [16384]

typedef _Float16 f16x2 __attribute__((ext_vector_type(2)));
typedef _Float16 f16x8 __attribute__((ext_vector_type(8)));
typedef float    f32x16 __attribute__((ext_vector_type(16)));

union f16x8_split { f16x8 v8; f16x2 v2[4]; };

__global__ void k_setup(const float* __restrict__ x_, const float* __restrict__ h_,
                        const float* __restrict__ W1, const float* __restrict__ b1,
                        const float* __restrict__ W2, const float* __restrict__ lw,
                        const float* __restrict__ sp, float* __restrict__ ws) {
    int b = blockIdx.x;
    int j = threadIdx.x;  // 128 threads
    short* wsh = (short*)ws;

    // c1[b][j] = b1[j] + sum_k W1[j][1+k] * h_[b][k]   (stored f16)
    float acc = b1[j];
    const float* w1row = W1 + j * IND;
    const float* hrow  = h_ + b * NHM1;
    #pragma unroll 7
    for (int k = 0; k < NHM1; ++k) acc = fmaf(w1row[1 + k], hrow[k], acc);
    {
        _Float16 hv = (_Float16)acc;
        short sv; __builtin_memcpy(&sv, &hv, 2);
        wsh[WSH_C1 + b * HD + j] = sv;
    }

    // xm[b] = sum_f x_[b][f] * lw[f]
    float s = 0.f;
    for (int k = j; k < NF; k += HD) s = fmaf(x_[b * NF + k], lw[k], s);
    __shared__ float red[HD];
    red[j] = s;
    __syncthreads();
    for (int off = 64; off > 0; off >>= 1) {
        if (j < off) red[j] += red[j + off];
        __syncthreads();
    }
    if (j == 0) ws[WS_XM + b] = red[0];

    // W2 fragment pack (A layout, 32x32x16):
    // table[((kk*4+nt)*64 + lane)*8 + i] = f16(W2[nt*32+(lane&31)][kk*16+(lane>>5)*8+i])
    if (b < 128) {
        int d = b * 128 + j;   // 0..16383
        int i = d & 7, lane = (d >> 3) & 63, kn = d >> 9;
        int kk = kn >> 2, nt = kn & 3;
        int row = nt * 32 + (lane & 31);
        int k = kk * 16 + (lane >> 5) * 8 + i;
        _Float16 hv = (_Float16)W2[row * HD + k];
        short sv; __builtin_memcpy(&sv, &hv, 2);
        wsh[WSH_W2F + d] = sv;
    }

    if (b == 0) {
        if (j < SS) {
            float acc2 = 0.f;
            for (int jj = 0; jj <= 50; jj += 2) {
                float wj = (jj == 0) ? 1.f : 2.f / (1.f - (float)(jj * jj));
                float lamv;
                if (j == 0 || j == 50) {
                    lamv = 0.02f;
                } else {
                    int m = (jj * j) % 100;
                    lamv = cosf((float)m * (float)M_PI / 50.f) * 0.04f;
                }
                acc2 = fmaf(lamv, wj, acc2);
            }
            ws[WS_CCW + j] = acc2;
            float st = cosf((float)j * (float)M_PI / 50.f);
            ws[WS_U + j] = (st + 1.f) * 0.5f;
        }
        if (j == 127) ws[WS_LAM] = 1.f / (1.f + expf(-sp[0]));
    }
    if (b == 2) {
        _Float16 hv = (_Float16)W1[j * IND];   // w1t column as f16
        short sv; __builtin_memcpy(&sv, &hv, 2);
        wsh[WSH_W1 + j] = sv;
    }
    if (b == 4) ws[WS_OUT1 + j] = 0.f;
    if (b == 5) ws[WS_OUT1 + 128 + j] = 0.f;
}

// One block = one batch row b; 4 INDEPENDENT waves, each owning 21 tiles of
// 32 evals (m-split). Per wave: full W2 as stationary A fragments (8kk x 4nt),
// B = a1 built in-register with per-lane t (col = eval = lane&31). D[j][eval]:
// col=lane -> j-reduction is in-register + one shfl_xor(32). NO barriers in
// the main loop; tail deferred one iteration via 2 carried registers.
// Empirical optimum across 8 structural regimes (r5..r15): 34.5 us/dispatch.
__launch_bounds__(256, 1)
__global__ void k_int(const float* __restrict__ b2, const float* __restrict__ W3,
                      const float* __restrict__ b3, const float* __restrict__ fw,
                      const float* __restrict__ ws, const float* __restrict__ outprev,
                      float* __restrict__ tgt, float* __restrict__ ztgt) {
    int b = blockIdx.x;
    int tid = threadIdx.x;
    int wv = tid >> 6, l = tid & 63;
    int e32 = l & 31, h2 = l >> 5;

    __shared__ float us[SS], ccs[SS], xw[4];

    if (ztgt && tid == 0) ztgt[b] = 0.f;   // zero next-step accumulator
    if (tid < SS) { us[tid] = ws[WS_U + tid]; ccs[tid] = ws[WS_CCW + tid]; }

    // xT / xmax prologue: xmax = max(0, max_b xT[b]) + 10
    float lam = ws[WS_LAM];
    float xmv = ws[WS_XM + tid];
    float opv = outprev ? outprev[tid] : 0.f;
    float xtv = (1.f - lam) * xmv + lam * opv;
    float mx = fmaxf(xtv, 0.f);
    #pragma unroll
    for (int off = 32; off >= 1; off >>= 1) mx = fmaxf(mx, __shfl_xor(mx, off, 64));
    if (l == 0) xw[wv] = mx;
    __syncthreads();
    float xmax = fmaxf(fmaxf(xw[0], xw[1]), fmaxf(xw[2], xw[3])) + 10.f;
    float xT = (1.f - lam) * ws[WS_XM + b] + lam * (outprev ? outprev[b] : 0.f);

    const short* wsh = (const short*)ws;

    // stationary: full W2 fragment set (128 regs, AGPR-eligible as MFMA A-src)
    f16x8 Af[8][4];
    #pragma unroll
    for (int kk = 0; kk < 8; ++kk)
        #pragma unroll
        for (int nt = 0; nt < 4; ++nt)
            Af[kk][nt] = *reinterpret_cast<const f16x8*>(
                wsh + WSH_W2F + ((kk * 4 + nt) * 64 + l) * 8);

    f16x2 c1p[8][4], w1p[8][4];
    #pragma unroll
    for (int kk = 0; kk < 8; ++kk) {
        f16x8_split c8, w8;
        c8.v8 = *reinterpret_cast<const f16x8*>(wsh + WSH_C1 + b * HD + kk * 16 + h2 * 8);
        w8.v8 = *reinterpret_cast<const f16x8*>(wsh + WSH_W1 + kk * 16 + h2 * 8);
        #pragma unroll
        for (int p = 0; p < 4; ++p) { c1p[kk][p] = c8.v2[p]; w1p[kk][p] = w8.v2[p]; }
    }

    float b2n[4][16], w3n[4][16];
    #pragma unroll
    for (int nt = 0; nt < 4; ++nt)
        #pragma unroll
        for (int r = 0; r < 16; ++r) {
            int j = nt * 32 + (r & 3) + 8 * (r >> 2) + 4 * h2;  // D-row for reg r
            b2n[nt][r] = b2[j]; w3n[nt][r] = W3[j];
        }
    float b3v = b3[0];
    float fw0 = fw[0], fw1 = fw[1], fw2 = fw[2], fw3 = fw[3], fw4 = fw[4];

    float accO = 0.f;
    float zs_prev = 0.f, w_prev = 0.f;   // deferred-tail carry

    #pragma unroll 1
    for (int it = 0; it < 21; ++it) {
        int m = (wv * 21 + it) * 32 + e32;      // this lane's eval
        int valid = (m <= 2600);
        int mm = valid ? m : 2600;
        int s  = (mm * 41121) >> 21;            // mm / 51 (exact for mm < 110376)
        int si = mm - s * 51;
        float x = xT * us[s];
        float range = xmax - x;
        float t = fmaf(range, us[si], x);
        float wgt = valid ? (ccs[si] * ccs[s] * range * xT * 0.25f) : 0.f;
        float wsel = h2 ? 0.f : wgt;            // h2=1 lanes duplicate -> contribute 0
        _Float16 th = (_Float16)t;
        f16x2 tv = {th, th};

        f32x16 C0, C1, C2, C3;
        #pragma unroll
        for (int e = 0; e < 16; ++e) {
            C0[e] = b2n[0][e]; C1[e] = b2n[1][e];
            C2[e] = b2n[2][e]; C3[e] = b2n[3][e];
        }

        // deferred tail for previous iter (overlaps this iter's MFMAs)
        {
            float z = zs_prev > 0.f ? zs_prev + 1.f : __expf(zs_prev);  // elu+1
            float sq = sqrtf(z);
            float p15 = z * sq, p2 = z * z, p25 = p2 * sq, p3 = p2 * z, p35 = p3 * sq;
            float g = fw0 * __builtin_amdgcn_rcpf(p15 + 1.f)
                    + fw1 * __builtin_amdgcn_rcpf(p2  + 1.f)
                    + fw2 * __builtin_amdgcn_rcpf(p25 + 1.f)
                    + fw3 * __builtin_amdgcn_rcpf(p3  + 1.f)
                    + fw4 * __builtin_amdgcn_rcpf(p35 + 1.f);
            g = fmaxf(g, 0.f);
            accO = fmaf(g, w_prev, accO);
        }

        const f16x2 z2 = {(_Float16)0.f, (_Float16)0.f};
        #pragma unroll
        for (int kk = 0; kk < 8; ++kk) {
            f16x8_split Bu;
            #pragma unroll
            for (int p = 0; p < 4; ++p)
                Bu.v2[p] = __builtin_elementwise_max(
                    __builtin_elementwise_fma(w1p[kk][p], tv, c1p[kk][p]), z2);
            C0 = __builtin_amdgcn_mfma_f32_32x32x16_f16(Af[kk][0], Bu.v8, C0, 0, 0, 0);
            C1 = __builtin_amdgcn_mfma_f32_32x32x16_f16(Af[kk][1], Bu.v8, C1, 0, 0, 0);
            C2 = __builtin_amdgcn_mfma_f32_32x32x16_f16(Af[kk][2], Bu.v8, C2, 0, 0, 0);
            C3 = __builtin_amdgcn_mfma_f32_32x32x16_f16(Af[kk][3], Bu.v8, C3, 0, 0, 0);
        }

        // j-reduction for this lane's eval: 64 j's here + 64 in lane^32
        float pa = 0.f, pb = 0.f, pc = 0.f, pd = 0.f;
        #pragma unroll
        for (int r = 0; r < 16; ++r) {
            pa = fmaf(fmaxf(C0[r], 0.f), w3n[0][r], pa);
            pb = fmaf(fmaxf(C1[r], 0.f), w3n[1][r], pb);
            pc = fmaf(fmaxf(C2[r], 0.f), w3n[2][r], pc);
            pd = fmaf(fmaxf(C3[r], 0.f), w3n[3][r], pd);
        }
        float z1 = (pa + pb) + (pc + pd);
        z1 += __shfl_xor(z1, 32, 64);           // fold h-halves: full z for eval l&31
        zs_prev = z1 + b3v;
        w_prev = wsel;
    }

    // final tail (iter 20)
    {
        float z = zs_prev > 0.f ? zs_prev + 1.f : __expf(zs_prev);
        float sq = sqrtf(z);
        float p15 = z * sq, p2 = z * z, p25 = p2 * sq, p3 = p2 * z, p35 = p3 * sq;
        float g = fw0 * __builtin_amdgcn_rcpf(p15 + 1.f)
                + fw1 * __builtin_amdgcn_rcpf(p2  + 1.f)
                + fw2 * __builtin_amdgcn_rcpf(p25 + 1.f)
                + fw3 * __builtin_amdgcn_rcpf(p3  + 1.f)
                + fw4 * __builtin_amdgcn_rcpf(p35 + 1.f);
        g = fmaxf(g, 0.f);
        accO = fmaf(g, w_prev, accO);
    }

    // wave-level reduce (h2=1 lanes hold 0), one atomic per wave
    #pragma unroll
    for (int off = 32; off >= 1; off >>= 1) accO += __shfl_xor(accO, off, 64);
    if (l == 0) atomicAdd(&tgt[b], accO);
}

extern "C" void kernel_launch(void* const* d_in, const int* in_sizes, int n_in,
                              void* d_out, int out_size, void* d_ws, size_t ws_size,
                              hipStream_t stream) {
    (void)in_sizes; (void)n_in; (void)out_size; (void)ws_size;
    const float* x_ = (const float*)d_in[0];
    const float* h_ = (const float*)d_in[1];
    const float* W1 = (const float*)d_in[2];
    const float* b1 = (const float*)d_in[3];
    const float* W2 = (const float*)d_in[4];
    const float* b2 = (const float*)d_in[5];
    const float* W3 = (const float*)d_in[6];
    const float* b3 = (const float*)d_in[7];
    const float* fw = (const float*)d_in[8];
    const float* lw = (const float*)d_in[9];
    const float* sp = (const float*)d_in[10];
    float* wsf  = (float*)d_ws;
    float* out1 = wsf + WS_OUT1;
    float* out  = (float*)d_out;

    // setup: c1, xm, CC tables, lam, W2 fragment pack, zero out1
    k_setup<<<BB, HD, 0, stream>>>(x_, h_, W1, b1, W2, lw, sp, wsf);
    // RNN step 0: xT=(1-lam)*xm (outprev=null); accumulate into out1; zero d_out
    k_int<<<BB, 256, 0, stream>>>(b2, W3, b3, fw, wsf, nullptr, out1, out);
    // RNN step 1: xT=(1-lam)*xm+lam*out1; accumulate into d_out
    k_int<<<BB, 256, 0, stream>>>(b2, W3, b3, fw, wsf, out1, out, nullptr);
}